// Round 8
// baseline (549.037 us; speedup 1.0000x reference)
//
#include <hip/hip_runtime.h>
#include <math.h>

#define NB 8
#define NN 2048

typedef short bf16x8 __attribute__((ext_vector_type(8)));
typedef float f32x4  __attribute__((ext_vector_type(4)));

__device__ __forceinline__ f32x4 mfma16(uint4 a, uint4 b, f32x4 c) {
    return __builtin_amdgcn_mfma_f32_16x16x32_bf16(
        __builtin_bit_cast(bf16x8, a), __builtin_bit_cast(bf16x8, b), c, 0, 0, 0);
}

__device__ __forceinline__ float rlf(float v, int l) {
    return __builtin_bit_cast(float, __builtin_amdgcn_readlane(__builtin_bit_cast(int, v), l));
}

__device__ __forceinline__ float bf2f(unsigned short u) {
    unsigned int t = ((unsigned int)u) << 16;
    return __builtin_bit_cast(float, t);
}

// Full sorted insert with jax tie-break (equal d -> smaller j) — for merges.
#define INS4(vv, ii, d, j) {                                      \
    bool c0 = (d < vv.x) || (d == vv.x && j < ii.x);              \
    bool c1 = (d < vv.y) || (d == vv.y && j < ii.y);              \
    bool c2 = (d < vv.z) || (d == vv.z && j < ii.z);              \
    bool c3 = (d < vv.w) || (d == vv.w && j < ii.w);              \
    vv.w = c3 ? (c2 ? vv.z : d) : vv.w; ii.w = c3 ? (c2 ? ii.z : j) : ii.w; \
    vv.z = c2 ? (c1 ? vv.y : d) : vv.z; ii.z = c2 ? (c1 ? ii.y : j) : ii.z; \
    vv.y = c1 ? (c0 ? vv.x : d) : vv.y; ii.y = c1 ? (c0 ? ii.x : j) : ii.y; \
    vv.x = c0 ? d : vv.x;               ii.x = c0 ? j : ii.x; }

// Strict-< insert: valid when candidates arrive in ascending j within a lane.
#define INS4S(vv, ii, d, j) {                                     \
    bool c0 = (d < vv.x); bool c1 = (d < vv.y);                   \
    bool c2 = (d < vv.z); bool c3 = (d < vv.w);                   \
    vv.w = c3 ? (c2 ? vv.z : d) : vv.w; ii.w = c3 ? (c2 ? ii.z : j) : ii.w; \
    vv.z = c2 ? (c1 ? vv.y : d) : vv.z; ii.z = c2 ? (c1 ? ii.y : j) : ii.z; \
    vv.y = c1 ? (c0 ? vv.x : d) : vv.y; ii.y = c1 ? (c0 ? ii.x : j) : ii.y; \
    vv.x = c0 ? d : vv.x;               ii.x = c0 ? j : ii.x; }

// ---------------- Kernel 1: embed MLP; emit frag-major 3-split HsF + sq ----------------
// block = 16 nodes = one MFMA 16-row group (group id == blockIdx.x).
// HsF layout: uint4 HsF[(group*6 + s*2+hf)*64 + lane] == A/B-frag register image:
//   row = lane&15, features hf*32 + (lane>>4)*8 .. +7 of split s.
__global__ __launch_bounds__(256) void k_embed(
    const float* __restrict__ x, const float* __restrict__ W1, const float* __restrict__ b1,
    const float* __restrict__ W2, const float* __restrict__ b2,
    uint4* __restrict__ HsF, float* __restrict__ sqv)
{
    __shared__ float w2s[4096];
    __shared__ float h1s[4][4][64];
    __shared__ unsigned short sh[3 * 16 * 72];   // [s][row][feat], stride 72
    int tid = threadIdx.x;
    for (int q = tid; q < 4096; q += 256) w2s[q] = W2[q];
    int wave = tid >> 6, lane = tid & 63;
    int nbase = blockIdx.x * 16 + wave * 4;
    float w10 = W1[lane], w11 = W1[64 + lane], w12 = W1[128 + lane], w13 = W1[192 + lane];
    float b1l = b1[lane];
    #pragma unroll
    for (int v = 0; v < 4; v++) {
        float4 xv = reinterpret_cast<const float4*>(x)[nbase + v];
        h1s[wave][v][lane] = fmaxf(b1l + xv.x * w10 + xv.y * w11 + xv.z * w12 + xv.w * w13, 0.f);
    }
    __syncthreads();
    float b2l = b2[lane];
    float a0 = b2l, a1 = b2l, a2 = b2l, a3 = b2l;
    for (int k = 0; k < 64; k++) {
        float w = w2s[k * 64 + lane];
        a0 += h1s[wave][0][k] * w; a1 += h1s[wave][1][k] * w;
        a2 += h1s[wave][2][k] * w; a3 += h1s[wave][3][k] * w;
    }
    float hvs[4] = {fmaxf(a0, 0.f), fmaxf(a1, 0.f), fmaxf(a2, 0.f), fmaxf(a3, 0.f)};
    #pragma unroll
    for (int v = 0; v < 4; v++) {
        float hval = hvs[v];
        long node = nbase + v;
        int row = wave * 4 + v;
        // exact 3-way truncation split: h == f0 + f1 + f2 (8+8+8 significand bits)
        unsigned int u0 = __builtin_bit_cast(unsigned int, hval);
        unsigned short s0 = (unsigned short)(u0 >> 16);
        float f0 = __builtin_bit_cast(float, u0 & 0xFFFF0000u);
        float r1 = hval - f0;
        unsigned int u1 = __builtin_bit_cast(unsigned int, r1);
        unsigned short s1 = (unsigned short)(u1 >> 16);
        float f1 = __builtin_bit_cast(float, u1 & 0xFFFF0000u);
        float r2 = r1 - f1;
        unsigned short s2 = (unsigned short)(__builtin_bit_cast(unsigned int, r2) >> 16);
        sh[(0 * 16 + row) * 72 + lane] = s0;
        sh[(1 * 16 + row) * 72 + lane] = s1;
        sh[(2 * 16 + row) * 72 + lane] = s2;
        float s = hval * hval;
        #pragma unroll
        for (int m = 1; m < 64; m <<= 1) s += __shfl_xor(s, m, 64);
        if (lane == 0) sqv[node] = s;
    }
    __syncthreads();
    // pack frags: 384 uint4 per block
    for (int q = tid; q < 384; q += 256) {
        int f = q >> 6, ln = q & 63;
        int s = f >> 1, hf = f & 1;
        int row = ln & 15, eb = hf * 32 + (ln >> 4) * 8;
        const unsigned short* sp = &sh[(s * 16 + row) * 72 + eb];
        unsigned int p0 = (unsigned int)sp[0] | ((unsigned int)sp[1] << 16);
        unsigned int p1 = (unsigned int)sp[2] | ((unsigned int)sp[3] << 16);
        unsigned int p2 = (unsigned int)sp[4] | ((unsigned int)sp[5] << 16);
        unsigned int p3 = (unsigned int)sp[6] | ((unsigned int)sp[7] << 16);
        HsF[((long)blockIdx.x * 6 + f) * 64 + ln] = make_uint4(p0, p1, p2, p3);
    }
}

// ---------------- Kernel 2: 3-NN partials via MFMA, frag-major loads, 32 i-rows/wave ----------------
// LDS kept at 33,792 B (< 64 KiB static limit) via two-phase merge.
__global__ __launch_bounds__(256, 2) void k_knn(
    const uint4* __restrict__ HsF, const float* __restrict__ sqv,
    float* __restrict__ pval, int* __restrict__ pidx)
{
    __shared__ float smv[4][1056];
    __shared__ int   smi[4][1056];

    int tid = threadIdx.x;
    int wave = tid >> 6, lane = tid & 63;
    int l15 = lane & 15, quad = lane >> 4;

    int job = blockIdx.x * 4 + wave;     // 0..2047
    int js  = job & 3;
    int g32 = job >> 2;                  // 0..511
    int b   = g32 >> 6;
    int i32 = g32 & 63;
    int gb  = b << 7;                    // 128 groups/batch
    int ig0 = i32 * 2;
    const float* sqb = sqv + ((long)b << 11);

    uint4 A[2][6];
    #pragma unroll
    for (int set = 0; set < 2; set++)
        #pragma unroll
        for (int f = 0; f < 6; f++)
            A[set][f] = HsF[((long)(gb + ig0 + set) * 6 + f) * 64 + lane];

    float4 val[2][4]; int4 idx[2][4];
    #pragma unroll
    for (int s = 0; s < 2; s++)
        #pragma unroll
        for (int r = 0; r < 4; r++) {
            val[s][r] = make_float4(3.4e38f, 3.4e38f, 3.4e38f, 3.4e38f);
            idx[s][r] = make_int4(0x7fffffff, 0x7fffffff, 0x7fffffff, 0x7fffffff);
        }

#define LOADB(B, SJ, G) {                                                     \
    _Pragma("unroll")                                                         \
    for (int f = 0; f < 6; f++)                                               \
        B[f] = HsF[((long)(gb + (G)) * 6 + f) * 64 + lane];                   \
    SJ = sqb[(G) * 16 + l15]; }

// d = sj - 2*dot (the +si shift is row-constant: ordering & ties unaffected)
#define COMPUTE(B, SJ, G) {                                                   \
    int j = (G) * 16 + l15;                                                   \
    _Pragma("unroll")                                                         \
    for (int set = 0; set < 2; set++) {                                       \
        f32x4 acc = {0.f, 0.f, 0.f, 0.f};                                     \
        _Pragma("unroll")                                                     \
        for (int hf = 0; hf < 2; hf++) {                                      \
            acc = mfma16(A[set][hf],     B[hf],     acc);                     \
            acc = mfma16(A[set][hf],     B[2 + hf], acc);                     \
            acc = mfma16(A[set][2 + hf], B[hf],     acc);                     \
            acc = mfma16(A[set][2 + hf], B[2 + hf], acc);                     \
            acc = mfma16(A[set][hf],     B[4 + hf], acc);                     \
            acc = mfma16(A[set][4 + hf], B[hf],     acc);                     \
        }                                                                     \
        _Pragma("unroll")                                                     \
        for (int r = 0; r < 4; r++) {                                         \
            float d = fmaf(-2.f, acc[r], SJ);                                 \
            INS4S(val[set][r], idx[set][r], d, j);                            \
        }                                                                     \
    } }

    int jg0 = js * 32;
    uint4 B0[6], B1[6];
    float sj0, sj1;
    LOADB(B0, sj0, jg0);
    #pragma unroll 1
    for (int t = 0; t < 16; t++) {
        int ga = jg0 + t * 2;
        int gbn = ga + 1;
        int gc = jg0 + ((t * 2 + 2) & 31);   // wraps on last iter (dummy prefetch)
        LOADB(B1, sj1, gbn);
        COMPUTE(B0, sj0, ga);
        LOADB(B0, sj0, gc);
        COMPUTE(B1, sj1, gbn);
    }

    // two-phase merge: 16 rows per phase, LDS region 1056 floats/ints per wave
    float* mv = smv[wave]; int* mi = smi[wave];
    #pragma unroll 1
    for (int set = 0; set < 2; set++) {
        #pragma unroll
        for (int r = 0; r < 4; r++) {
            int base = (quad * 4 + r) * 65 + l15 * 4;
            mv[base + 0] = val[set][r].x; mv[base + 1] = val[set][r].y;
            mv[base + 2] = val[set][r].z; mv[base + 3] = val[set][r].w;
            mi[base + 0] = idx[set][r].x; mi[base + 1] = idx[set][r].y;
            mi[base + 2] = idx[set][r].z; mi[base + 3] = idx[set][r].w;
        }
        __syncthreads();
        // lane handles row l15, chunk quad merges 4 of the 16 lists
        float4 fv = make_float4(3.4e38f, 3.4e38f, 3.4e38f, 3.4e38f);
        int4   fi = make_int4(0x7fffffff, 0x7fffffff, 0x7fffffff, 0x7fffffff);
        #pragma unroll
        for (int tt = 0; tt < 4; tt++) {
            int base = l15 * 65 + (quad * 4 + tt) * 4;
            #pragma unroll
            for (int k = 0; k < 4; k++) {
                float d = mv[base + k];
                int j = mi[base + k];
                INS4(fv, fi, d, j);
            }
        }
        // butterfly across quads (xor 16, 32)
        #pragma unroll
        for (int m = 16; m <= 32; m <<= 1) {
            float ov0 = __shfl_xor(fv.x, m, 64), ov1 = __shfl_xor(fv.y, m, 64);
            float ov2 = __shfl_xor(fv.z, m, 64), ov3 = __shfl_xor(fv.w, m, 64);
            int   oi0 = __shfl_xor(fi.x, m, 64), oi1 = __shfl_xor(fi.y, m, 64);
            int   oi2 = __shfl_xor(fi.z, m, 64), oi3 = __shfl_xor(fi.w, m, 64);
            INS4(fv, fi, ov0, oi0); INS4(fv, fi, ov1, oi1);
            INS4(fv, fi, ov2, oi2); INS4(fv, fi, ov3, oi3);
        }
        if (quad == 0) {
            long gi = ((long)b << 11) + i32 * 32 + set * 16 + l15;
            pval[gi * 16 + js * 4 + 0] = fv.x; pidx[gi * 16 + js * 4 + 0] = fi.x;
            pval[gi * 16 + js * 4 + 1] = fv.y; pidx[gi * 16 + js * 4 + 1] = fi.y;
            pval[gi * 16 + js * 4 + 2] = fv.z; pidx[gi * 16 + js * 4 + 2] = fi.z;
            pval[gi * 16 + js * 4 + 3] = fv.w; pidx[gi * 16 + js * 4 + 3] = fi.w;
        }
        __syncthreads();
    }
}

// ---------------- Kernel 2b: merge 4 j-split partials -> knn[3] ----------------
__global__ __launch_bounds__(256) void k_knn_merge(
    const float* __restrict__ pval, const int* __restrict__ pidx, int* __restrict__ knn)
{
    int gi = blockIdx.x * 256 + threadIdx.x;
    float4 fv = make_float4(3.4e38f, 3.4e38f, 3.4e38f, 3.4e38f);
    int4   fi = make_int4(0x7fffffff, 0x7fffffff, 0x7fffffff, 0x7fffffff);
    #pragma unroll
    for (int t = 0; t < 16; t++) {
        float d = pval[(long)gi * 16 + t];
        int j = pidx[(long)gi * 16 + t];
        INS4(fv, fi, d, j);
    }
    int* o = knn + (long)gi * 3;
    o[0] = fi.y; o[1] = fi.z; o[2] = fi.w;
}

// ---------------- Kernel 3: head, registerized; h reconstructed bit-exactly from HsF ----------------
// wave = 4 nodes; lane F holds feature F (and F+64 of the 128-vecs).
__global__ __launch_bounds__(256) void k_head(
    const unsigned short* __restrict__ HsU, const int* __restrict__ knn,
    const float* __restrict__ Wm, const float* __restrict__ bm,
    const float* __restrict__ Wu1, const float* __restrict__ bu1,
    const float* __restrict__ Wu2, const float* __restrict__ bu2,
    const float* __restrict__ Wmean, const float* __restrict__ bmean,
    const float* __restrict__ Wv, const float* __restrict__ bv,
    const float* __restrict__ log_std,
    float* __restrict__ out_mean, float* __restrict__ out_std, float* __restrict__ out_val)
{
    int tid = threadIdx.x;
    int wave = tid >> 6, lane = tid & 63;
    int base = blockIdx.x * 16 + wave * 4;

    // frag coordinates of feature `lane`
    int hf = lane >> 5, qd = (lane >> 3) & 3, fe = lane & 7;
    long lanoff = ((long)hf * 64 + qd * 16) * 8 + fe;

    // gather h rows: exact reconstruction f0+f1+f2
    float nr[4][3], hc0[4];
    #pragma unroll
    for (int nl = 0; nl < 4; nl++) {
        int node = base + nl;
        int bt = (node >> 11) << 11;
        {
            const unsigned short* p = HsU + ((long)(node >> 4) * 6) * 512 + (node & 15) * 8 + lanoff;
            hc0[nl] = bf2f(p[0]) + bf2f(p[1024]) + bf2f(p[2048]);
        }
        #pragma unroll
        for (int en = 0; en < 3; en++) {
            int gn = bt + knn[node * 3 + en];
            const unsigned short* p = HsU + ((long)(gn >> 4) * 6) * 512 + (gn & 15) * 8 + lanoff;
            nr[nl][en] = bf2f(p[0]) + bf2f(p[1024]) + bf2f(p[2048]);
        }
    }

    // msgs: out-feature = lane
    float am[4][3];
    {
        float bmf = bm[lane];
        #pragma unroll
        for (int nl = 0; nl < 4; nl++)
            #pragma unroll
            for (int en = 0; en < 3; en++) am[nl][en] = bmf;
        #pragma unroll
        for (int k = 0; k < 64; k++) {
            float wv = Wm[k * 64 + lane];
            #pragma unroll
            for (int nl = 0; nl < 4; nl++)
                #pragma unroll
                for (int en = 0; en < 3; en++)
                    am[nl][en] = fmaf(rlf(nr[nl][en], k), wv, am[nl][en]);
        }
    }
    float hc1[4];
    #pragma unroll
    for (int nl = 0; nl < 4; nl++)
        hc1[nl] = (fmaxf(am[nl][0], 0.f) + fmaxf(am[nl][1], 0.f) + fmaxf(am[nl][2], 0.f)) * (1.f / 3.f);

    // u1 = relu(hc @ Wu1 + bu1)
    float ub0[4], ub1[4];
    {
        float a0[4], a1[4];
        float b0 = bu1[lane], b1v = bu1[64 + lane];
        #pragma unroll
        for (int nl = 0; nl < 4; nl++) { a0[nl] = b0; a1[nl] = b1v; }
        #pragma unroll
        for (int k = 0; k < 64; k++) {
            float w0 = Wu1[k * 128 + lane];
            float w1 = Wu1[k * 128 + 64 + lane];
            #pragma unroll
            for (int nl = 0; nl < 4; nl++) {
                float s = rlf(hc0[nl], k);
                a0[nl] = fmaf(s, w0, a0[nl]); a1[nl] = fmaf(s, w1, a1[nl]);
            }
        }
        #pragma unroll
        for (int k = 0; k < 64; k++) {
            float w0 = Wu1[(64 + k) * 128 + lane];
            float w1 = Wu1[(64 + k) * 128 + 64 + lane];
            #pragma unroll
            for (int nl = 0; nl < 4; nl++) {
                float s = rlf(hc1[nl], k);
                a0[nl] = fmaf(s, w0, a0[nl]); a1[nl] = fmaf(s, w1, a1[nl]);
            }
        }
        #pragma unroll
        for (int nl = 0; nl < 4; nl++) { ub0[nl] = fmaxf(a0[nl], 0.f); ub1[nl] = fmaxf(a1[nl], 0.f); }
    }

    // u2 = relu(u1 @ Wu2 + bu2)
    float u20[4], u21[4];
    {
        float a0[4], a1[4];
        float b0 = bu2[lane], b1v = bu2[64 + lane];
        #pragma unroll
        for (int nl = 0; nl < 4; nl++) { a0[nl] = b0; a1[nl] = b1v; }
        #pragma unroll
        for (int k = 0; k < 64; k++) {
            float w0 = Wu2[k * 128 + lane];
            float w1 = Wu2[k * 128 + 64 + lane];
            #pragma unroll
            for (int nl = 0; nl < 4; nl++) {
                float s = rlf(ub0[nl], k);
                a0[nl] = fmaf(s, w0, a0[nl]); a1[nl] = fmaf(s, w1, a1[nl]);
            }
        }
        #pragma unroll
        for (int k = 0; k < 64; k++) {
            float w0 = Wu2[(64 + k) * 128 + lane];
            float w1 = Wu2[(64 + k) * 128 + 64 + lane];
            #pragma unroll
            for (int nl = 0; nl < 4; nl++) {
                float s = rlf(ub1[nl], k);
                a0[nl] = fmaf(s, w0, a0[nl]); a1[nl] = fmaf(s, w1, a1[nl]);
            }
        }
        #pragma unroll
        for (int nl = 0; nl < 4; nl++) { u20[nl] = fmaxf(a0[nl], 0.f); u21[nl] = fmaxf(a1[nl], 0.f); }
    }

    // heads
    float wm0a = Wmean[lane * 2 + 0], wm0b = Wmean[(64 + lane) * 2 + 0];
    float wm1a = Wmean[lane * 2 + 1], wm1b = Wmean[(64 + lane) * 2 + 1];
    float wva  = Wv[lane],            wvb  = Wv[64 + lane];
    #pragma unroll
    for (int nl = 0; nl < 4; nl++) {
        float p0 = u20[nl] * wm0a + u21[nl] * wm0b;
        float p1 = u20[nl] * wm1a + u21[nl] * wm1b;
        float p2 = u20[nl] * wva  + u21[nl] * wvb;
        #pragma unroll
        for (int m = 1; m < 64; m <<= 1) {
            p0 += __shfl_xor(p0, m, 64);
            p1 += __shfl_xor(p1, m, 64);
            p2 += __shfl_xor(p2, m, 64);
        }
        if (lane == 0) {
            int node = base + nl;
            out_mean[node * 2 + 0] = p0 + bmean[0];
            out_mean[node * 2 + 1] = p1 + bmean[1];
            out_val[node] = p2 + bv[0];
        }
    }
    if (blockIdx.x == 0 && tid < 2) out_std[tid] = expf(log_std[tid]);
}

extern "C" void kernel_launch(void* const* d_in, const int* in_sizes, int n_in,
                              void* d_out, int out_size, void* d_ws, size_t ws_size,
                              hipStream_t stream) {
    const float* x     = (const float*)d_in[0];
    const float* W1    = (const float*)d_in[1];
    const float* b1    = (const float*)d_in[2];
    const float* W2    = (const float*)d_in[3];
    const float* b2    = (const float*)d_in[4];
    const float* Wm    = (const float*)d_in[5];
    const float* bm    = (const float*)d_in[6];
    const float* Wu1   = (const float*)d_in[7];
    const float* bu1   = (const float*)d_in[8];
    const float* Wu2   = (const float*)d_in[9];
    const float* bu2   = (const float*)d_in[10];
    const float* Wmean = (const float*)d_in[11];
    const float* bmean = (const float*)d_in[12];
    const float* Wv    = (const float*)d_in[13];
    const float* bv    = (const float*)d_in[14];
    const float* lstd  = (const float*)d_in[15];

    float* out = (float*)d_out;
    float* out_mean = out;                 // 8*2048*2
    float* out_std  = out + 32768;         // 2
    float* out_val  = out + 32770;         // 8*2048

    // workspace: identical 8,650,752-byte footprint to round 5 (passing)
    uint4* HsF  = (uint4*)d_ws;                              // 1024*6*64 uint4 = 6 MB
    float* sqv  = (float*)(HsF + (long)1024 * 6 * 64);       // 64 KB
    int*   knn  = (int*)(sqv + 16384);                       // 192 KB
    float* pval = (float*)(knn + 16384 * 3);                 // 1 MB
    int*   pidx = (int*)(pval + (long)16384 * 16);           // 1 MB

    k_embed<<<1024, 256, 0, stream>>>(x, W1, b1, W2, b2, HsF, sqv);
    k_knn<<<512, 256, 0, stream>>>(HsF, sqv, pval, pidx);
    k_knn_merge<<<64, 256, 0, stream>>>(pval, pidx, knn);
    k_head<<<1024, 256, 0, stream>>>((const unsigned short*)HsF, knn, Wm, bm, Wu1, bu1, Wu2, bu2,
                                     Wmean, bmean, Wv, bv, lstd,
                                     out_mean, out_std, out_val);
}

// Round 9
// 244.292 us; speedup vs baseline: 2.2475x; 2.2475x over previous
//
#include <hip/hip_runtime.h>
#include <math.h>

#define NB 8
#define NN 2048

typedef short bf16x8 __attribute__((ext_vector_type(8)));
typedef float f32x4  __attribute__((ext_vector_type(4)));

__device__ __forceinline__ f32x4 mfma16(uint4 a, uint4 b, f32x4 c) {
    return __builtin_amdgcn_mfma_f32_16x16x32_bf16(
        __builtin_bit_cast(bf16x8, a), __builtin_bit_cast(bf16x8, b), c, 0, 0, 0);
}

__device__ __forceinline__ float bf2f(unsigned short u) {
    unsigned int t = ((unsigned int)u) << 16;
    return __builtin_bit_cast(float, t);
}

// Full sorted insert with jax tie-break (equal d -> smaller j) — for merges.
#define INS4(vv, ii, d, j) {                                      \
    bool c0 = (d < vv.x) || (d == vv.x && j < ii.x);              \
    bool c1 = (d < vv.y) || (d == vv.y && j < ii.y);              \
    bool c2 = (d < vv.z) || (d == vv.z && j < ii.z);              \
    bool c3 = (d < vv.w) || (d == vv.w && j < ii.w);              \
    vv.w = c3 ? (c2 ? vv.z : d) : vv.w; ii.w = c3 ? (c2 ? ii.z : j) : ii.w; \
    vv.z = c2 ? (c1 ? vv.y : d) : vv.z; ii.z = c2 ? (c1 ? ii.y : j) : ii.z; \
    vv.y = c1 ? (c0 ? vv.x : d) : vv.y; ii.y = c1 ? (c0 ? ii.x : j) : ii.y; \
    vv.x = c0 ? d : vv.x;               ii.x = c0 ? j : ii.x; }

// Strict-< insert: valid when candidates arrive in ascending j within a lane.
#define INS4S(vv, ii, d, j) {                                     \
    bool c0 = (d < vv.x); bool c1 = (d < vv.y);                   \
    bool c2 = (d < vv.z); bool c3 = (d < vv.w);                   \
    vv.w = c3 ? (c2 ? vv.z : d) : vv.w; ii.w = c3 ? (c2 ? ii.z : j) : ii.w; \
    vv.z = c2 ? (c1 ? vv.y : d) : vv.z; ii.z = c2 ? (c1 ? ii.y : j) : ii.z; \
    vv.y = c1 ? (c0 ? vv.x : d) : vv.y; ii.y = c1 ? (c0 ? ii.x : j) : ii.y; \
    vv.x = c0 ? d : vv.x;               ii.x = c0 ? j : ii.x; }

// ---------------- Kernel 1: embed MLP; emit frag-major 3-split HsF + sq ----------------
// block = 16 nodes = one MFMA 16-row group (group id == blockIdx.x).
// HsF layout: uint4 HsF[(group*6 + s*2+hf)*64 + lane] == A/B-frag register image:
//   row = lane&15, features hf*32 + (lane>>4)*8 .. +7 of split s.
__global__ __launch_bounds__(256) void k_embed(
    const float* __restrict__ x, const float* __restrict__ W1, const float* __restrict__ b1,
    const float* __restrict__ W2, const float* __restrict__ b2,
    uint4* __restrict__ HsF, float* __restrict__ sqv)
{
    __shared__ float w2s[4096];
    __shared__ float h1s[4][4][64];
    __shared__ unsigned short sh[3 * 16 * 72];   // [s][row][feat], stride 72
    int tid = threadIdx.x;
    for (int q = tid; q < 4096; q += 256) w2s[q] = W2[q];
    int wave = tid >> 6, lane = tid & 63;
    int nbase = blockIdx.x * 16 + wave * 4;
    float w10 = W1[lane], w11 = W1[64 + lane], w12 = W1[128 + lane], w13 = W1[192 + lane];
    float b1l = b1[lane];
    #pragma unroll
    for (int v = 0; v < 4; v++) {
        float4 xv = reinterpret_cast<const float4*>(x)[nbase + v];
        h1s[wave][v][lane] = fmaxf(b1l + xv.x * w10 + xv.y * w11 + xv.z * w12 + xv.w * w13, 0.f);
    }
    __syncthreads();
    float b2l = b2[lane];
    float a0 = b2l, a1 = b2l, a2 = b2l, a3 = b2l;
    for (int k = 0; k < 64; k++) {
        float w = w2s[k * 64 + lane];
        a0 += h1s[wave][0][k] * w; a1 += h1s[wave][1][k] * w;
        a2 += h1s[wave][2][k] * w; a3 += h1s[wave][3][k] * w;
    }
    float hvs[4] = {fmaxf(a0, 0.f), fmaxf(a1, 0.f), fmaxf(a2, 0.f), fmaxf(a3, 0.f)};
    #pragma unroll
    for (int v = 0; v < 4; v++) {
        float hval = hvs[v];
        long node = nbase + v;
        int row = wave * 4 + v;
        // exact 3-way truncation split: h == f0 + f1 + f2 (8+8+8 significand bits)
        unsigned int u0 = __builtin_bit_cast(unsigned int, hval);
        unsigned short s0 = (unsigned short)(u0 >> 16);
        float f0 = __builtin_bit_cast(float, u0 & 0xFFFF0000u);
        float r1 = hval - f0;
        unsigned int u1 = __builtin_bit_cast(unsigned int, r1);
        unsigned short s1 = (unsigned short)(u1 >> 16);
        float f1 = __builtin_bit_cast(float, u1 & 0xFFFF0000u);
        float r2 = r1 - f1;
        unsigned short s2 = (unsigned short)(__builtin_bit_cast(unsigned int, r2) >> 16);
        sh[(0 * 16 + row) * 72 + lane] = s0;
        sh[(1 * 16 + row) * 72 + lane] = s1;
        sh[(2 * 16 + row) * 72 + lane] = s2;
        float s = hval * hval;
        #pragma unroll
        for (int m = 1; m < 64; m <<= 1) s += __shfl_xor(s, m, 64);
        if (lane == 0) sqv[node] = s;
    }
    __syncthreads();
    // pack frags: 384 uint4 per block
    for (int q = tid; q < 384; q += 256) {
        int f = q >> 6, ln = q & 63;
        int s = f >> 1, hf = f & 1;
        int row = ln & 15, eb = hf * 32 + (ln >> 4) * 8;
        const unsigned short* sp = &sh[(s * 16 + row) * 72 + eb];
        unsigned int p0 = (unsigned int)sp[0] | ((unsigned int)sp[1] << 16);
        unsigned int p1 = (unsigned int)sp[2] | ((unsigned int)sp[3] << 16);
        unsigned int p2 = (unsigned int)sp[4] | ((unsigned int)sp[5] << 16);
        unsigned int p3 = (unsigned int)sp[6] | ((unsigned int)sp[7] << 16);
        HsF[((long)blockIdx.x * 6 + f) * 64 + ln] = make_uint4(p0, p1, p2, p3);
    }
}

// ---------------- Kernel 2: 3-NN partials via MFMA, frag-major loads, 32 i-rows/wave ----------------
// LDS 33,792 B; merge phases are compile-time (SET literal) so val/idx stay in VGPRs.
__global__ __launch_bounds__(256, 2) void k_knn(
    const uint4* __restrict__ HsF, const float* __restrict__ sqv,
    float* __restrict__ pval, int* __restrict__ pidx)
{
    __shared__ float smv[4][1056];
    __shared__ int   smi[4][1056];

    int tid = threadIdx.x;
    int wave = tid >> 6, lane = tid & 63;
    int l15 = lane & 15, quad = lane >> 4;

    int job = blockIdx.x * 4 + wave;     // 0..2047
    int js  = job & 3;
    int g32 = job >> 2;                  // 0..511
    int b   = g32 >> 6;
    int i32 = g32 & 63;
    int gb  = b << 7;                    // 128 groups/batch
    int ig0 = i32 * 2;
    const float* sqb = sqv + ((long)b << 11);

    uint4 A[2][6];
    #pragma unroll
    for (int set = 0; set < 2; set++)
        #pragma unroll
        for (int f = 0; f < 6; f++)
            A[set][f] = HsF[((long)(gb + ig0 + set) * 6 + f) * 64 + lane];

    float4 val[2][4]; int4 idx[2][4];
    #pragma unroll
    for (int s = 0; s < 2; s++)
        #pragma unroll
        for (int r = 0; r < 4; r++) {
            val[s][r] = make_float4(3.4e38f, 3.4e38f, 3.4e38f, 3.4e38f);
            idx[s][r] = make_int4(0x7fffffff, 0x7fffffff, 0x7fffffff, 0x7fffffff);
        }

#define LOADB(B, SJ, G) {                                                     \
    _Pragma("unroll")                                                         \
    for (int f = 0; f < 6; f++)                                               \
        B[f] = HsF[((long)(gb + (G)) * 6 + f) * 64 + lane];                   \
    SJ = sqb[(G) * 16 + l15]; }

// d = sj - 2*dot (the +si shift is row-constant: ordering & ties unaffected)
#define COMPUTE(B, SJ, G) {                                                   \
    int j = (G) * 16 + l15;                                                   \
    _Pragma("unroll")                                                         \
    for (int set = 0; set < 2; set++) {                                       \
        f32x4 acc = {0.f, 0.f, 0.f, 0.f};                                     \
        _Pragma("unroll")                                                     \
        for (int hf = 0; hf < 2; hf++) {                                      \
            acc = mfma16(A[set][hf],     B[hf],     acc);                     \
            acc = mfma16(A[set][hf],     B[2 + hf], acc);                     \
            acc = mfma16(A[set][2 + hf], B[hf],     acc);                     \
            acc = mfma16(A[set][2 + hf], B[2 + hf], acc);                     \
            acc = mfma16(A[set][hf],     B[4 + hf], acc);                     \
            acc = mfma16(A[set][4 + hf], B[hf],     acc);                     \
        }                                                                     \
        _Pragma("unroll")                                                     \
        for (int r = 0; r < 4; r++) {                                         \
            float d = fmaf(-2.f, acc[r], SJ);                                 \
            INS4S(val[set][r], idx[set][r], d, j);                            \
        }                                                                     \
    } }

    int jg0 = js * 32;
    uint4 B0[6], B1[6];
    float sj0, sj1;
    LOADB(B0, sj0, jg0);
    #pragma unroll 1
    for (int t = 0; t < 16; t++) {
        int ga = jg0 + t * 2;
        int gbn = ga + 1;
        int gc = jg0 + ((t * 2 + 2) & 31);   // wraps on last iter (dummy prefetch)
        LOADB(B1, sj1, gbn);
        COMPUTE(B0, sj0, ga);
        LOADB(B0, sj0, gc);
        COMPUTE(B1, sj1, gbn);
    }

    // two-phase merge, SET is a compile-time literal -> no scratch demotion
    float* mv = smv[wave]; int* mi = smi[wave];
#define MERGE_PHASE(SET) {                                                    \
    _Pragma("unroll")                                                         \
    for (int r = 0; r < 4; r++) {                                             \
        int base = (quad * 4 + r) * 65 + l15 * 4;                             \
        mv[base + 0] = val[SET][r].x; mv[base + 1] = val[SET][r].y;           \
        mv[base + 2] = val[SET][r].z; mv[base + 3] = val[SET][r].w;           \
        mi[base + 0] = idx[SET][r].x; mi[base + 1] = idx[SET][r].y;           \
        mi[base + 2] = idx[SET][r].z; mi[base + 3] = idx[SET][r].w;           \
    }                                                                         \
    __syncthreads();                                                          \
    float4 fv = make_float4(3.4e38f, 3.4e38f, 3.4e38f, 3.4e38f);              \
    int4   fi = make_int4(0x7fffffff, 0x7fffffff, 0x7fffffff, 0x7fffffff);    \
    _Pragma("unroll")                                                         \
    for (int tt = 0; tt < 4; tt++) {                                          \
        int base = l15 * 65 + (quad * 4 + tt) * 4;                            \
        _Pragma("unroll")                                                     \
        for (int k = 0; k < 4; k++) {                                         \
            float d = mv[base + k];                                           \
            int j = mi[base + k];                                             \
            INS4(fv, fi, d, j);                                               \
        }                                                                     \
    }                                                                         \
    _Pragma("unroll")                                                         \
    for (int m = 16; m <= 32; m <<= 1) {                                      \
        float ov0 = __shfl_xor(fv.x, m, 64), ov1 = __shfl_xor(fv.y, m, 64);   \
        float ov2 = __shfl_xor(fv.z, m, 64), ov3 = __shfl_xor(fv.w, m, 64);   \
        int   oi0 = __shfl_xor(fi.x, m, 64), oi1 = __shfl_xor(fi.y, m, 64);   \
        int   oi2 = __shfl_xor(fi.z, m, 64), oi3 = __shfl_xor(fi.w, m, 64);   \
        INS4(fv, fi, ov0, oi0); INS4(fv, fi, ov1, oi1);                       \
        INS4(fv, fi, ov2, oi2); INS4(fv, fi, ov3, oi3);                       \
    }                                                                         \
    if (quad == 0) {                                                          \
        long gi = ((long)b << 11) + i32 * 32 + (SET) * 16 + l15;              \
        pval[gi * 16 + js * 4 + 0] = fv.x; pidx[gi * 16 + js * 4 + 0] = fi.x; \
        pval[gi * 16 + js * 4 + 1] = fv.y; pidx[gi * 16 + js * 4 + 1] = fi.y; \
        pval[gi * 16 + js * 4 + 2] = fv.z; pidx[gi * 16 + js * 4 + 2] = fi.z; \
        pval[gi * 16 + js * 4 + 3] = fv.w; pidx[gi * 16 + js * 4 + 3] = fi.w; \
    }                                                                         \
    __syncthreads(); }

    MERGE_PHASE(0)
    MERGE_PHASE(1)
}

// ---------------- Kernel 2b: merge 4 j-split partials -> knn[3] ----------------
__global__ __launch_bounds__(256) void k_knn_merge(
    const float* __restrict__ pval, const int* __restrict__ pidx, int* __restrict__ knn)
{
    int gi = blockIdx.x * 256 + threadIdx.x;
    float4 fv = make_float4(3.4e38f, 3.4e38f, 3.4e38f, 3.4e38f);
    int4   fi = make_int4(0x7fffffff, 0x7fffffff, 0x7fffffff, 0x7fffffff);
    #pragma unroll
    for (int t = 0; t < 16; t++) {
        float d = pval[(long)gi * 16 + t];
        int j = pidx[(long)gi * 16 + t];
        INS4(fv, fi, d, j);
    }
    int* o = knn + (long)gi * 3;
    o[0] = fi.y; o[1] = fi.z; o[2] = fi.w;
}

// ---------------- Kernel 3: head, round-5 LDS-broadcast structure ----------------
// 32 nodes/block, 8 per wave; h reconstructed bit-exactly from frag-major HsF.
__global__ __launch_bounds__(256) void k_head(
    const unsigned short* __restrict__ HsU, const int* __restrict__ knn,
    const float* __restrict__ Wm, const float* __restrict__ bm,
    const float* __restrict__ Wu1, const float* __restrict__ bu1,
    const float* __restrict__ Wu2, const float* __restrict__ bu2,
    const float* __restrict__ Wmean, const float* __restrict__ bmean,
    const float* __restrict__ Wv, const float* __restrict__ bv,
    const float* __restrict__ log_std,
    float* __restrict__ out_mean, float* __restrict__ out_std, float* __restrict__ out_val)
{
    __shared__ float neigh[4][8 * 3 * 64];   // 24 KB
    __shared__ float hc[4][8][128];          // 16 KB
    __shared__ float ub[4][8][128];          // 16 KB

    int tid = threadIdx.x;
    int wave = tid >> 6, lane = tid & 63;
    int base = blockIdx.x * 32 + wave * 8;

    // frag coordinates of feature `lane`: ushort offset within a group's 3072-ushort block
    int hfc = lane >> 5, qd = (lane >> 3) & 3, fe = lane & 7;
    long lanoff = (long)hfc * 512 + qd * 128 + fe;

    // gather: lane reconstructs feature `lane` of each needed row (exact f0+f1+f2)
    #pragma unroll
    for (int nl = 0; nl < 8; nl++) {
        int node = base + nl;
        int bt = (node >> 11) << 11;
        const unsigned short* p = HsU + (long)(node >> 4) * 3072 + (node & 15) * 8 + lanoff;
        hc[wave][nl][lane] = bf2f(p[0]) + bf2f(p[1024]) + bf2f(p[2048]);
        #pragma unroll
        for (int en = 0; en < 3; en++) {
            int gn = bt + knn[node * 3 + en];
            const unsigned short* q = HsU + (long)(gn >> 4) * 3072 + (gn & 15) * 8 + lanoff;
            neigh[wave][(nl * 3 + en) * 64 + lane] = bf2f(q[0]) + bf2f(q[1024]) + bf2f(q[2048]);
        }
    }
    __syncthreads();

    // msgs
    {
        float am[8][3];
        float bmf = bm[lane];
        #pragma unroll
        for (int nl = 0; nl < 8; nl++)
            #pragma unroll
            for (int e = 0; e < 3; e++) am[nl][e] = bmf;
        for (int k = 0; k < 64; k++) {
            float w = Wm[k * 64 + lane];
            #pragma unroll
            for (int nl = 0; nl < 8; nl++)
                #pragma unroll
                for (int e = 0; e < 3; e++)
                    am[nl][e] += neigh[wave][(nl * 3 + e) * 64 + k] * w;
        }
        #pragma unroll
        for (int nl = 0; nl < 8; nl++) {
            float m = (fmaxf(am[nl][0], 0.f) + fmaxf(am[nl][1], 0.f) + fmaxf(am[nl][2], 0.f)) * (1.f / 3.f);
            hc[wave][nl][64 + lane] = m;
        }
    }
    __syncthreads();

    // u1
    {
        float a0[8], a1[8];
        float b0 = bu1[lane], b1v = bu1[64 + lane];
        #pragma unroll
        for (int nl = 0; nl < 8; nl++) { a0[nl] = b0; a1[nl] = b1v; }
        for (int k = 0; k < 128; k++) {
            float w0 = Wu1[k * 128 + lane];
            float w1 = Wu1[k * 128 + 64 + lane];
            #pragma unroll
            for (int nl = 0; nl < 8; nl++) {
                float v = hc[wave][nl][k];
                a0[nl] += v * w0; a1[nl] += v * w1;
            }
        }
        #pragma unroll
        for (int nl = 0; nl < 8; nl++) {
            ub[wave][nl][lane]      = fmaxf(a0[nl], 0.f);
            ub[wave][nl][64 + lane] = fmaxf(a1[nl], 0.f);
        }
    }
    __syncthreads();

    // u2 in regs
    float u20[8], u21[8];
    {
        float b0 = bu2[lane], b1v = bu2[64 + lane];
        #pragma unroll
        for (int nl = 0; nl < 8; nl++) { u20[nl] = b0; u21[nl] = b1v; }
        for (int k = 0; k < 128; k++) {
            float w0 = Wu2[k * 128 + lane];
            float w1 = Wu2[k * 128 + 64 + lane];
            #pragma unroll
            for (int nl = 0; nl < 8; nl++) {
                float v = ub[wave][nl][k];
                u20[nl] += v * w0; u21[nl] += v * w1;
            }
        }
        #pragma unroll
        for (int nl = 0; nl < 8; nl++) { u20[nl] = fmaxf(u20[nl], 0.f); u21[nl] = fmaxf(u21[nl], 0.f); }
    }

    float wm0a = Wmean[lane * 2 + 0], wm0b = Wmean[(64 + lane) * 2 + 0];
    float wm1a = Wmean[lane * 2 + 1], wm1b = Wmean[(64 + lane) * 2 + 1];
    float wva  = Wv[lane],            wvb  = Wv[64 + lane];
    #pragma unroll
    for (int nl = 0; nl < 8; nl++) {
        float p0 = u20[nl] * wm0a + u21[nl] * wm0b;
        float p1 = u20[nl] * wm1a + u21[nl] * wm1b;
        float p2 = u20[nl] * wva  + u21[nl] * wvb;
        #pragma unroll
        for (int m = 1; m < 64; m <<= 1) {
            p0 += __shfl_xor(p0, m, 64);
            p1 += __shfl_xor(p1, m, 64);
            p2 += __shfl_xor(p2, m, 64);
        }
        if (lane == 0) {
            int node = base + nl;
            out_mean[node * 2 + 0] = p0 + bmean[0];
            out_mean[node * 2 + 1] = p1 + bmean[1];
            out_val[node] = p2 + bv[0];
        }
    }
    if (blockIdx.x == 0 && tid < 2) out_std[tid] = expf(log_std[tid]);
}

extern "C" void kernel_launch(void* const* d_in, const int* in_sizes, int n_in,
                              void* d_out, int out_size, void* d_ws, size_t ws_size,
                              hipStream_t stream) {
    const float* x     = (const float*)d_in[0];
    const float* W1    = (const float*)d_in[1];
    const float* b1    = (const float*)d_in[2];
    const float* W2    = (const float*)d_in[3];
    const float* b2    = (const float*)d_in[4];
    const float* Wm    = (const float*)d_in[5];
    const float* bm    = (const float*)d_in[6];
    const float* Wu1   = (const float*)d_in[7];
    const float* bu1   = (const float*)d_in[8];
    const float* Wu2   = (const float*)d_in[9];
    const float* bu2   = (const float*)d_in[10];
    const float* Wmean = (const float*)d_in[11];
    const float* bmean = (const float*)d_in[12];
    const float* Wv    = (const float*)d_in[13];
    const float* bv    = (const float*)d_in[14];
    const float* lstd  = (const float*)d_in[15];

    float* out = (float*)d_out;
    float* out_mean = out;                 // 8*2048*2
    float* out_std  = out + 32768;         // 2
    float* out_val  = out + 32770;         // 8*2048

    // workspace: identical 8,650,752-byte footprint to rounds 4/5/8 (passing)
    uint4* HsF  = (uint4*)d_ws;                              // 1024*6*64 uint4 = 6 MB
    float* sqv  = (float*)(HsF + (long)1024 * 6 * 64);       // 64 KB
    int*   knn  = (int*)(sqv + 16384);                       // 192 KB
    float* pval = (float*)(knn + 16384 * 3);                 // 1 MB
    int*   pidx = (int*)(pval + (long)16384 * 16);           // 1 MB

    k_embed<<<1024, 256, 0, stream>>>(x, W1, b1, W2, b2, HsF, sqv);
    k_knn<<<512, 256, 0, stream>>>(HsF, sqv, pval, pidx);
    k_knn_merge<<<64, 256, 0, stream>>>(pval, pidx, knn);
    k_head<<<512, 256, 0, stream>>>((const unsigned short*)HsF, knn, Wm, bm, Wu1, bu1, Wu2, bu2,
                                    Wmean, bmean, Wv, bv, lstd,
                                    out_mean, out_std, out_val);
}

// Round 10
// 203.496 us; speedup vs baseline: 2.6980x; 1.2005x over previous
//
#include <hip/hip_runtime.h>
#include <math.h>

#define NB 8
#define NN 2048

typedef short bf16x8 __attribute__((ext_vector_type(8)));
typedef float f32x4  __attribute__((ext_vector_type(4)));

__device__ __forceinline__ f32x4 mfma16(uint4 a, uint4 b, f32x4 c) {
    return __builtin_amdgcn_mfma_f32_16x16x32_bf16(
        __builtin_bit_cast(bf16x8, a), __builtin_bit_cast(bf16x8, b), c, 0, 0, 0);
}

__device__ __forceinline__ float bf2f(unsigned short u) {
    unsigned int t = ((unsigned int)u) << 16;
    return __builtin_bit_cast(float, t);
}

__device__ __forceinline__ unsigned short f2bf_rne(float f) {
    unsigned int u = __builtin_bit_cast(unsigned int, f);
    return (unsigned short)((u + 0x7FFFu + ((u >> 16) & 1u)) >> 16);
}

// merge three packed bf16-pairs (splits s0,s1,s2) into RNE-rounded bf16 pair of the exact sum
__device__ __forceinline__ unsigned int rne_pair(unsigned int a, unsigned int b, unsigned int c) {
    float lo = bf2f((unsigned short)(a & 0xFFFF)) + bf2f((unsigned short)(b & 0xFFFF)) + bf2f((unsigned short)(c & 0xFFFF));
    float hi = bf2f((unsigned short)(a >> 16)) + bf2f((unsigned short)(b >> 16)) + bf2f((unsigned short)(c >> 16));
    return (unsigned int)f2bf_rne(lo) | ((unsigned int)f2bf_rne(hi) << 16);
}
__device__ __forceinline__ uint4 rne_merge(uint4 a, uint4 b, uint4 c) {
    return make_uint4(rne_pair(a.x, b.x, c.x), rne_pair(a.y, b.y, c.y),
                      rne_pair(a.z, b.z, c.z), rne_pair(a.w, b.w, c.w));
}

// Full sorted insert with jax tie-break (equal d -> smaller j) — for merges.
#define INS4(vv, ii, d, j) {                                      \
    bool c0 = (d < vv.x) || (d == vv.x && j < ii.x);              \
    bool c1 = (d < vv.y) || (d == vv.y && j < ii.y);              \
    bool c2 = (d < vv.z) || (d == vv.z && j < ii.z);              \
    bool c3 = (d < vv.w) || (d == vv.w && j < ii.w);              \
    vv.w = c3 ? (c2 ? vv.z : d) : vv.w; ii.w = c3 ? (c2 ? ii.z : j) : ii.w; \
    vv.z = c2 ? (c1 ? vv.y : d) : vv.z; ii.z = c2 ? (c1 ? ii.y : j) : ii.z; \
    vv.y = c1 ? (c0 ? vv.x : d) : vv.y; ii.y = c1 ? (c0 ? ii.x : j) : ii.y; \
    vv.x = c0 ? d : vv.x;               ii.x = c0 ? j : ii.x; }

// Strict-< insert: valid when candidates arrive in ascending j within a lane.
#define INS4S(vv, ii, d, j) {                                     \
    bool c0 = (d < vv.x); bool c1 = (d < vv.y);                   \
    bool c2 = (d < vv.z); bool c3 = (d < vv.w);                   \
    vv.w = c3 ? (c2 ? vv.z : d) : vv.w; ii.w = c3 ? (c2 ? ii.z : j) : ii.w; \
    vv.z = c2 ? (c1 ? vv.y : d) : vv.z; ii.z = c2 ? (c1 ? ii.y : j) : ii.z; \
    vv.y = c1 ? (c0 ? vv.x : d) : vv.y; ii.y = c1 ? (c0 ? ii.x : j) : ii.y; \
    vv.x = c0 ? d : vv.x;               ii.x = c0 ? j : ii.x; }

// ---------------- Kernel 1: embed MLP; emit frag-major 3-split HsF + sq ----------------
// HsF layout: uint4 HsF[(group*6 + s*2+hf)*64 + ln], ln = part*16 + row:
//   row = node within group, features hf*32 + part*8 .. +7 of split s.
__global__ __launch_bounds__(256) void k_embed(
    const float* __restrict__ x, const float* __restrict__ W1, const float* __restrict__ b1,
    const float* __restrict__ W2, const float* __restrict__ b2,
    uint4* __restrict__ HsF, float* __restrict__ sqv)
{
    __shared__ float w2s[4096];
    __shared__ float h1s[4][4][64];
    __shared__ unsigned short sh[3 * 16 * 72];
    int tid = threadIdx.x;
    for (int q = tid; q < 4096; q += 256) w2s[q] = W2[q];
    int wave = tid >> 6, lane = tid & 63;
    int nbase = blockIdx.x * 16 + wave * 4;
    float w10 = W1[lane], w11 = W1[64 + lane], w12 = W1[128 + lane], w13 = W1[192 + lane];
    float b1l = b1[lane];
    #pragma unroll
    for (int v = 0; v < 4; v++) {
        float4 xv = reinterpret_cast<const float4*>(x)[nbase + v];
        h1s[wave][v][lane] = fmaxf(b1l + xv.x * w10 + xv.y * w11 + xv.z * w12 + xv.w * w13, 0.f);
    }
    __syncthreads();
    float b2l = b2[lane];
    float a0 = b2l, a1 = b2l, a2 = b2l, a3 = b2l;
    for (int k = 0; k < 64; k++) {
        float w = w2s[k * 64 + lane];
        a0 += h1s[wave][0][k] * w; a1 += h1s[wave][1][k] * w;
        a2 += h1s[wave][2][k] * w; a3 += h1s[wave][3][k] * w;
    }
    float hvs[4] = {fmaxf(a0, 0.f), fmaxf(a1, 0.f), fmaxf(a2, 0.f), fmaxf(a3, 0.f)};
    #pragma unroll
    for (int v = 0; v < 4; v++) {
        float hval = hvs[v];
        long node = nbase + v;
        int row = wave * 4 + v;
        unsigned int u0 = __builtin_bit_cast(unsigned int, hval);
        unsigned short s0 = (unsigned short)(u0 >> 16);
        float f0 = __builtin_bit_cast(float, u0 & 0xFFFF0000u);
        float r1 = hval - f0;
        unsigned int u1 = __builtin_bit_cast(unsigned int, r1);
        unsigned short s1 = (unsigned short)(u1 >> 16);
        float f1 = __builtin_bit_cast(float, u1 & 0xFFFF0000u);
        float r2 = r1 - f1;
        unsigned short s2 = (unsigned short)(__builtin_bit_cast(unsigned int, r2) >> 16);
        sh[(0 * 16 + row) * 72 + lane] = s0;
        sh[(1 * 16 + row) * 72 + lane] = s1;
        sh[(2 * 16 + row) * 72 + lane] = s2;
        float s = hval * hval;
        #pragma unroll
        for (int m = 1; m < 64; m <<= 1) s += __shfl_xor(s, m, 64);
        if (lane == 0) sqv[node] = s;
    }
    __syncthreads();
    for (int q = tid; q < 384; q += 256) {
        int f = q >> 6, ln = q & 63;
        int s = f >> 1, hf = f & 1;
        int row = ln & 15, eb = hf * 32 + (ln >> 4) * 8;
        const unsigned short* sp = &sh[(s * 16 + row) * 72 + eb];
        unsigned int p0 = (unsigned int)sp[0] | ((unsigned int)sp[1] << 16);
        unsigned int p1 = (unsigned int)sp[2] | ((unsigned int)sp[3] << 16);
        unsigned int p2 = (unsigned int)sp[4] | ((unsigned int)sp[5] << 16);
        unsigned int p3 = (unsigned int)sp[6] | ((unsigned int)sp[7] << 16);
        HsF[((long)blockIdx.x * 6 + f) * 64 + ln] = make_uint4(p0, p1, p2, p3);
    }
}

// ---------------- Kernel 2: 3-NN partials via MFMA, 16 i-rows/wave, low reg pressure ----------------
// Block: 4 waves = 4 consecutive i-groups sweeping the SAME j-split (B frags L1-shared).
__global__ __launch_bounds__(256, 3) void k_knn(
    const uint4* __restrict__ HsF, const float* __restrict__ sqv,
    float* __restrict__ pval, int* __restrict__ pidx)
{
    __shared__ float smv[4][1056];
    __shared__ int   smi[4][1056];

    int tid = threadIdx.x;
    int wave = tid >> 6, lane = tid & 63;
    int l15 = lane & 15, quad = lane >> 4;

    int bx = blockIdx.x;                 // 0..1023
    int js = bx & 3;
    int gquad = (bx >> 2) & 31;
    int b = bx >> 7;
    int gwb = gquad * 4 + wave;          // group within batch 0..127
    long g = (long)b * 128 + gwb;
    const float* sqb = sqv + ((long)b << 11);

    uint4 A[6];
    #pragma unroll
    for (int f = 0; f < 6; f++)
        A[f] = HsF[(g * 6 + f) * 64 + lane];

    float4 val[4]; int4 idx[4];
    #pragma unroll
    for (int r = 0; r < 4; r++) {
        val[r] = make_float4(3.4e38f, 3.4e38f, 3.4e38f, 3.4e38f);
        idx[r] = make_int4(0x7fffffff, 0x7fffffff, 0x7fffffff, 0x7fffffff);
    }

#define LOADB(B, SJ, G) {                                                     \
    long fb = ((long)b * 128 + (G)) * 6;                                      \
    _Pragma("unroll")                                                         \
    for (int f = 0; f < 6; f++)                                               \
        B[f] = HsF[(fb + f) * 64 + lane];                                     \
    SJ = sqb[(G) * 16 + l15]; }

// d = sj - 2*dot (the +si shift is row-constant: ordering & ties unaffected)
#define COMPUTE(B, SJ, G) {                                                   \
    int j = (G) * 16 + l15;                                                   \
    f32x4 acc = {0.f, 0.f, 0.f, 0.f};                                         \
    _Pragma("unroll")                                                         \
    for (int hf = 0; hf < 2; hf++) {                                          \
        acc = mfma16(A[hf],     B[hf],     acc);                              \
        acc = mfma16(A[hf],     B[2 + hf], acc);                              \
        acc = mfma16(A[2 + hf], B[hf],     acc);                              \
        acc = mfma16(A[2 + hf], B[2 + hf], acc);                              \
        acc = mfma16(A[hf],     B[4 + hf], acc);                              \
        acc = mfma16(A[4 + hf], B[hf],     acc);                              \
    }                                                                         \
    _Pragma("unroll")                                                         \
    for (int r = 0; r < 4; r++) {                                             \
        float d = fmaf(-2.f, acc[r], SJ);                                     \
        INS4S(val[r], idx[r], d, j);                                          \
    } }

    int jg0 = js * 32;
    uint4 B0[6], B1[6];
    float sj0, sj1;
    LOADB(B0, sj0, jg0);
    #pragma unroll 1
    for (int t = 0; t < 16; t++) {
        int ga = jg0 + t * 2;
        int gbn = ga + 1;
        int gc = jg0 + ((t * 2 + 2) & 31);   // wraps on last iter (dummy prefetch)
        LOADB(B1, sj1, gbn);
        COMPUTE(B0, sj0, ga);
        LOADB(B0, sj0, gc);
        COMPUTE(B1, sj1, gbn);
    }

    // single-phase merge (round-4 proven): stash 16 rows x 16 lists x 4
    float* mv = smv[wave]; int* mi = smi[wave];
    #pragma unroll
    for (int r = 0; r < 4; r++) {
        int base = (quad * 4 + r) * 65 + l15 * 4;
        mv[base + 0] = val[r].x; mv[base + 1] = val[r].y;
        mv[base + 2] = val[r].z; mv[base + 3] = val[r].w;
        mi[base + 0] = idx[r].x; mi[base + 1] = idx[r].y;
        mi[base + 2] = idx[r].z; mi[base + 3] = idx[r].w;
    }
    __syncthreads();
    float4 fv = make_float4(3.4e38f, 3.4e38f, 3.4e38f, 3.4e38f);
    int4   fi = make_int4(0x7fffffff, 0x7fffffff, 0x7fffffff, 0x7fffffff);
    #pragma unroll
    for (int tt = 0; tt < 4; tt++) {
        int base = l15 * 65 + (quad * 4 + tt) * 4;
        #pragma unroll
        for (int k = 0; k < 4; k++) {
            float d = mv[base + k];
            int j = mi[base + k];
            INS4(fv, fi, d, j);
        }
    }
    #pragma unroll
    for (int m = 16; m <= 32; m <<= 1) {
        float ov0 = __shfl_xor(fv.x, m, 64), ov1 = __shfl_xor(fv.y, m, 64);
        float ov2 = __shfl_xor(fv.z, m, 64), ov3 = __shfl_xor(fv.w, m, 64);
        int   oi0 = __shfl_xor(fi.x, m, 64), oi1 = __shfl_xor(fi.y, m, 64);
        int   oi2 = __shfl_xor(fi.z, m, 64), oi3 = __shfl_xor(fi.w, m, 64);
        INS4(fv, fi, ov0, oi0); INS4(fv, fi, ov1, oi1);
        INS4(fv, fi, ov2, oi2); INS4(fv, fi, ov3, oi3);
    }
    if (quad == 0) {
        long gi = ((long)b << 11) + gwb * 16 + l15;
        pval[gi * 16 + js * 4 + 0] = fv.x; pidx[gi * 16 + js * 4 + 0] = fi.x;
        pval[gi * 16 + js * 4 + 1] = fv.y; pidx[gi * 16 + js * 4 + 1] = fi.y;
        pval[gi * 16 + js * 4 + 2] = fv.z; pidx[gi * 16 + js * 4 + 2] = fi.z;
        pval[gi * 16 + js * 4 + 3] = fv.w; pidx[gi * 16 + js * 4 + 3] = fi.w;
    }
}

// ---------------- Kernel 2b: merge 4 j-split partials -> knn[3] ----------------
__global__ __launch_bounds__(256) void k_knn_merge(
    const float* __restrict__ pval, const int* __restrict__ pidx, int* __restrict__ knn)
{
    int gi = blockIdx.x * 256 + threadIdx.x;
    float4 fv = make_float4(3.4e38f, 3.4e38f, 3.4e38f, 3.4e38f);
    int4   fi = make_int4(0x7fffffff, 0x7fffffff, 0x7fffffff, 0x7fffffff);
    #pragma unroll
    for (int t = 0; t < 16; t++) {
        float d = pval[(long)gi * 16 + t];
        int j = pidx[(long)gi * 16 + t];
        INS4(fv, fi, d, j);
    }
    int* o = knn + (long)gi * 3;
    o[0] = fi.y; o[1] = fi.z; o[2] = fi.w;
}

// ---------------- Kernel 3: head via bf16 MFMA GEMMs ----------------
// Block = 4 waves = 4 groups (64 nodes). Weights RNE-bf16 in LDS frag images.
// msgs: 3x(16x64 @ 64x64); u1/u2: 16x128 @ 128x128; heads in fp32 VALU.
__global__ __launch_bounds__(256) void k_head(
    const uint4* __restrict__ HsF, const int* __restrict__ knn,
    const float* __restrict__ Wm, const float* __restrict__ bm,
    const float* __restrict__ Wu1, const float* __restrict__ bu1,
    const float* __restrict__ Wu2, const float* __restrict__ bu2,
    const float* __restrict__ Wmean, const float* __restrict__ bmean,
    const float* __restrict__ Wv, const float* __restrict__ bv,
    const float* __restrict__ log_std,
    float* __restrict__ out_mean, float* __restrict__ out_std, float* __restrict__ out_val)
{
    __shared__ __align__(16) uint4 wmf[8 * 64];            // 8 KB  (Wm^T frags)
    __shared__ __align__(16) uint4 wuf[32 * 64];           // 32 KB (Wu1 then Wu2 frags)
    __shared__ __align__(16) unsigned short hcT[4][16 * 136]; // 17 KB (hc, then u1) per-wave

    int tid = threadIdx.x;
    int wave = tid >> 6, lane = tid & 63;
    int l15 = lane & 15, quad = lane >> 4;
    long g = blockIdx.x * 4 + wave;      // group 0..1023
    int b = (int)(g >> 7);

    // ---- stage Wm^T frags (RNE bf16) ----
    for (int q = tid; q < 512; q += 256) {
        int fi2 = q >> 6, ln = q & 63;
        int fg = fi2 >> 1, hf = fi2 & 1;
        int fr = ln & 15, qd = ln >> 4;
        unsigned int p[4];
        #pragma unroll
        for (int e2 = 0; e2 < 4; e2++) {
            unsigned int lo = f2bf_rne(Wm[(hf * 32 + qd * 8 + e2 * 2 + 0) * 64 + fg * 16 + fr]);
            unsigned int hi = f2bf_rne(Wm[(hf * 32 + qd * 8 + e2 * 2 + 1) * 64 + fg * 16 + fr]);
            p[e2] = lo | (hi << 16);
        }
        wmf[q] = make_uint4(p[0], p[1], p[2], p[3]);
    }
#define STAGE_WU(W) {                                                         \
    for (int q = tid; q < 2048; q += 256) {                                   \
        int fi2 = q >> 6, ln = q & 63;                                        \
        int fg = fi2 >> 2, kq = fi2 & 3;                                      \
        int fr = ln & 15, qd = ln >> 4;                                       \
        unsigned int p[4];                                                    \
        _Pragma("unroll")                                                     \
        for (int e2 = 0; e2 < 4; e2++) {                                      \
            unsigned int lo = f2bf_rne(W[(kq * 32 + qd * 8 + e2 * 2 + 0) * 128 + fg * 16 + fr]); \
            unsigned int hi = f2bf_rne(W[(kq * 32 + qd * 8 + e2 * 2 + 1) * 128 + fg * 16 + fr]); \
            p[e2] = lo | (hi << 16);                                          \
        }                                                                     \
        wuf[q] = make_uint4(p[0], p[1], p[2], p[3]);                          \
    } }
    STAGE_WU(Wu1)

    // ---- gather A-frags: own h + 3 neighbors, exact-reconstruct then RNE ----
    uint4 hA[2];
    #pragma unroll
    for (int hf = 0; hf < 2; hf++)
        hA[hf] = rne_merge(HsF[(g * 6 + hf) * 64 + lane],
                           HsF[(g * 6 + 2 + hf) * 64 + lane],
                           HsF[(g * 6 + 4 + hf) * 64 + lane]);
    uint4 nA[3][2];
    {
        int node0 = (int)g * 16 + l15;
        #pragma unroll
        for (int e = 0; e < 3; e++) {
            int jn = knn[node0 * 3 + e];
            long gj = (long)b * 128 + (jn >> 4);
            int ln2 = quad * 16 + (jn & 15);
            #pragma unroll
            for (int hf = 0; hf < 2; hf++)
                nA[e][hf] = rne_merge(HsF[(gj * 6 + hf) * 64 + ln2],
                                      HsF[(gj * 6 + 2 + hf) * 64 + ln2],
                                      HsF[(gj * 6 + 4 + hf) * 64 + ln2]);
        }
    }
    // write own h into hcT (row = l15, cols hf*32+quad*8..+7)
    #pragma unroll
    for (int hf = 0; hf < 2; hf++)
        *reinterpret_cast<uint4*>(&hcT[wave][l15 * 136 + hf * 32 + quad * 8]) = hA[hf];
    __syncthreads();

    // ---- msgs GEMM: 3 x (A=neigh_e 16x64) @ (B=Wm^T) ----
    {
        uint4 wm_r[4][2];
        #pragma unroll
        for (int fg = 0; fg < 4; fg++)
            #pragma unroll
            for (int hf = 0; hf < 2; hf++)
                wm_r[fg][hf] = wmf[(fg * 2 + hf) * 64 + lane];
        float bmv[4];
        #pragma unroll
        for (int fg = 0; fg < 4; fg++) bmv[fg] = bm[fg * 16 + l15];
        f32x4 msum[4];
        #pragma unroll
        for (int fg = 0; fg < 4; fg++) msum[fg] = (f32x4){0.f, 0.f, 0.f, 0.f};
        #pragma unroll
        for (int e = 0; e < 3; e++)
            #pragma unroll
            for (int fg = 0; fg < 4; fg++) {
                f32x4 c = {0.f, 0.f, 0.f, 0.f};
                c = mfma16(nA[e][0], wm_r[fg][0], c);
                c = mfma16(nA[e][1], wm_r[fg][1], c);
                #pragma unroll
                for (int r = 0; r < 4; r++) msum[fg][r] += fmaxf(c[r] + bmv[fg], 0.f);
            }
        // write msgs (col 64 + fg*16 + l15, row = quad*4+r)
        #pragma unroll
        for (int fg = 0; fg < 4; fg++)
            #pragma unroll
            for (int r = 0; r < 4; r++)
                hcT[wave][(quad * 4 + r) * 136 + 64 + fg * 16 + l15] = f2bf_rne(msum[fg][r] * (1.f / 3.f));
    }
    __syncthreads();

    // ---- u1 GEMM: (hc 16x128) @ Wu1 ----
    unsigned short u1s[8][4];
    {
        uint4 a1[4];
        #pragma unroll
        for (int kq = 0; kq < 4; kq++)
            a1[kq] = *reinterpret_cast<const uint4*>(&hcT[wave][l15 * 136 + kq * 32 + quad * 8]);
        #pragma unroll
        for (int fg = 0; fg < 8; fg++) {
            float bv1 = bu1[fg * 16 + l15];
            f32x4 c = {0.f, 0.f, 0.f, 0.f};
            #pragma unroll
            for (int kq = 0; kq < 4; kq++)
                c = mfma16(a1[kq], wuf[(fg * 4 + kq) * 64 + lane], c);
            #pragma unroll
            for (int r = 0; r < 4; r++) u1s[fg][r] = f2bf_rne(fmaxf(c[r] + bv1, 0.f));
        }
        // overwrite hcT with u1 (row = quad*4+r, col = fg*16+l15)
        #pragma unroll
        for (int fg = 0; fg < 8; fg++)
            #pragma unroll
            for (int r = 0; r < 4; r++)
                hcT[wave][(quad * 4 + r) * 136 + fg * 16 + l15] = u1s[fg][r];
    }
    __syncthreads();
    STAGE_WU(Wu2)
    __syncthreads();

    // ---- u2 GEMM ----
    float u2v[8][4];
    {
        uint4 a2[4];
        #pragma unroll
        for (int kq = 0; kq < 4; kq++)
            a2[kq] = *reinterpret_cast<const uint4*>(&hcT[wave][l15 * 136 + kq * 32 + quad * 8]);
        #pragma unroll
        for (int fg = 0; fg < 8; fg++) {
            float bv2 = bu2[fg * 16 + l15];
            f32x4 c = {0.f, 0.f, 0.f, 0.f};
            #pragma unroll
            for (int kq = 0; kq < 4; kq++)
                c = mfma16(a2[kq], wuf[(fg * 4 + kq) * 64 + lane], c);
            #pragma unroll
            for (int r = 0; r < 4; r++) u2v[fg][r] = fmaxf(c[r] + bv2, 0.f);
        }
    }

    // ---- heads (fp32 VALU + 16-lane reduce) ----
    {
        float wm0[8], wm1[8], wvv[8];
        #pragma unroll
        for (int fg = 0; fg < 8; fg++) {
            int f = fg * 16 + l15;
            wm0[fg] = Wmean[f * 2 + 0];
            wm1[fg] = Wmean[f * 2 + 1];
            wvv[fg] = Wv[f];
        }
        float bm0 = bmean[0], bm1 = bmean[1], bv0 = bv[0];
        #pragma unroll
        for (int r = 0; r < 4; r++) {
            float p0 = 0.f, p1 = 0.f, p2 = 0.f;
            #pragma unroll
            for (int fg = 0; fg < 8; fg++) {
                p0 = fmaf(u2v[fg][r], wm0[fg], p0);
                p1 = fmaf(u2v[fg][r], wm1[fg], p1);
                p2 = fmaf(u2v[fg][r], wvv[fg], p2);
            }
            #pragma unroll
            for (int m = 1; m < 16; m <<= 1) {
                p0 += __shfl_xor(p0, m, 64);
                p1 += __shfl_xor(p1, m, 64);
                p2 += __shfl_xor(p2, m, 64);
            }
            if (l15 == 0) {
                int node = (int)g * 16 + quad * 4 + r;
                out_mean[node * 2 + 0] = p0 + bm0;
                out_mean[node * 2 + 1] = p1 + bm1;
                out_val[node] = p2 + bv0;
            }
        }
    }
    if (blockIdx.x == 0 && tid < 2) out_std[tid] = expf(log_std[tid]);
}

extern "C" void kernel_launch(void* const* d_in, const int* in_sizes, int n_in,
                              void* d_out, int out_size, void* d_ws, size_t ws_size,
                              hipStream_t stream) {
    const float* x     = (const float*)d_in[0];
    const float* W1    = (const float*)d_in[1];
    const float* b1    = (const float*)d_in[2];
    const float* W2    = (const float*)d_in[3];
    const float* b2    = (const float*)d_in[4];
    const float* Wm    = (const float*)d_in[5];
    const float* bm    = (const float*)d_in[6];
    const float* Wu1   = (const float*)d_in[7];
    const float* bu1   = (const float*)d_in[8];
    const float* Wu2   = (const float*)d_in[9];
    const float* bu2   = (const float*)d_in[10];
    const float* Wmean = (const float*)d_in[11];
    const float* bmean = (const float*)d_in[12];
    const float* Wv    = (const float*)d_in[13];
    const float* bv    = (const float*)d_in[14];
    const float* lstd  = (const float*)d_in[15];

    float* out = (float*)d_out;
    float* out_mean = out;                 // 8*2048*2
    float* out_std  = out + 32768;         // 2
    float* out_val  = out + 32770;         // 8*2048

    // workspace: identical 8,650,752-byte footprint to rounds 4/5/8/9 (passing)
    uint4* HsF  = (uint4*)d_ws;                              // 1024*6*64 uint4 = 6 MB
    float* sqv  = (float*)(HsF + (long)1024 * 6 * 64);       // 64 KB
    int*   knn  = (int*)(sqv + 16384);                       // 192 KB
    float* pval = (float*)(knn + 16384 * 3);                 // 1 MB
    int*   pidx = (int*)(pval + (long)16384 * 16);           // 1 MB

    k_embed<<<1024, 256, 0, stream>>>(x, W1, b1, W2, b2, HsF, sqv);
    k_knn<<<1024, 256, 0, stream>>>(HsF, sqv, pval, pidx);
    k_knn_merge<<<64, 256, 0, stream>>>(pval, pidx, knn);
    k_head<<<256, 256, 0, stream>>>(HsF, knn, Wm, bm, Wu1, bu1, Wu2, bu2,
                                    Wmean, bmean, Wv, bv, lstd,
                                    out_mean, out_std, out_val);
}